// Round 6
// baseline (716.606 us; speedup 1.0000x reference)
//
#include <hip/hip_runtime.h>
#include <stdint.h>

#define NB   4096   // batch rows
#define LDIM 4096   // latent dim
#define KK   10     // k
#define TPB  256
#define CAP  1024   // survivor buffer entries (u64) -> 8 KB LDS

typedef float fx4 __attribute__((ext_vector_type(4)));

__device__ __forceinline__ unsigned long long wave_min_u64(unsigned long long v) {
#pragma unroll
    for (int off = 1; off < 64; off <<= 1) {
        const unsigned long long o = __shfl_xor(v, off, 64);
        if (o < v) v = o;
    }
    return v;
}

// ============================================================================
// Kernel 1: selection. One block per row. Emits:
//   meta[b][s]  = pos(12b) | fm<<12 (10b mask over rows c flipping slot s) | sign<<22
//   basebits[b][w] = bit j of word w  <->  (logits[b][32w+j] > 0)
//   distr row + entropy partial
// ============================================================================
__global__ __launch_bounds__(TPB) void select_rows(
    const float* __restrict__ logits,
    float* __restrict__ distr,      // [NB, KK]
    float* __restrict__ entp,       // [NB]
    unsigned* __restrict__ meta,    // [NB, KK]
    unsigned* __restrict__ basebits)// [NB, 128]
{
    __shared__ float s_wsum[4];
    __shared__ int   s_pos[KK];
    __shared__ int   s_sign[KK];
    __shared__ int   s_bestm[KK];
    __shared__ int   s_cnt;
    __shared__ unsigned s_base[128];
    __shared__ unsigned long long s_cand[CAP];

    const int b    = blockIdx.x;
    const int t    = threadIdx.x;
    const int lane = t & 63;
    const int wv   = t >> 6;
    const float* __restrict__ row = logits + (size_t)b * LDIM;

    // coalesced row load: element i=4q+e -> col (q<<10) + 4t + e
    float vals[16];
#pragma unroll
    for (int q = 0; q < 4; q++) {
        const float4 f = *(const float4*)(row + (q << 10) + (t << 2));
        vals[q*4+0] = f.x; vals[q*4+1] = f.y; vals[q*4+2] = f.z; vals[q*4+3] = f.w;
    }

    // S0 = sum of positive logits (identical reduction order to passing kernel)
    float s0 = 0.f;
#pragma unroll
    for (int i = 0; i < 16; i++) s0 += vals[i] > 0.f ? vals[i] : 0.f;
#pragma unroll
    for (int off = 1; off < 64; off <<= 1) s0 += __shfl_xor(s0, off, 64);
    if (lane == 0) s_wsum[wv] = s0;

    if (t < 128) s_base[t] = 0u;
    __syncthreads();
    // base-sign bitmask: col (q<<10)+4t+e -> word (q<<5)+(t>>3), bit 4*(t&7)+e
#pragma unroll
    for (int q = 0; q < 4; q++) {
        unsigned nib = 0u;
#pragma unroll
        for (int e = 0; e < 4; e++)
            nib |= (vals[q*4+e] > 0.f ? 1u : 0u) << e;
        atomicOr(&s_base[(q << 5) + (t >> 3)], nib << (4 * (t & 7)));
    }

    // threshold compaction (exact; retry + full-rescan fallback)
    float T = 0.02f;
    int cnt = 0;
    for (int attempt = 0; attempt < 15; attempt++) {
        if (t == 0) s_cnt = 0;
        __syncthreads();
#pragma unroll
        for (int i = 0; i < 16; i++) {
            const float v    = vals[i];
            const float cost = fabsf(v);
            if (cost < T) {
                const int idx = ((i >> 2) << 10) + (t << 2) + (i & 3);
                const unsigned long long pk =
                    ((unsigned long long)__float_as_uint(cost) << 32)
                    | (unsigned)((idx << 1) | (v > 0.f ? 1 : 0));
                const int p = atomicAdd(&s_cnt, 1);
                if (p < CAP) s_cand[p] = pk;
            }
        }
        __syncthreads();
        cnt = s_cnt;
        if (cnt >= KK && cnt <= CAP) break;
        T = (cnt < KK) ? T * 4.0f : T * 0.25f;
        __syncthreads();
    }

    // basebits store (t<128 spans waves 0-1; s_base finalized by loop's barriers)
    if (t < 128) basebits[b * 128 + t] = s_base[t];

    if (wv != 0) return;

    const float S0 = (s_wsum[0] + s_wsum[1]) + (s_wsum[2] + s_wsum[3]);
    float csm[KK];
    unsigned long long prev = 0ull;

    if (cnt >= KK && cnt <= CAP) {
        const int nc = cnt;
#pragma unroll
        for (int c = 0; c < KK; c++) {
            unsigned long long best = ~0ull;
            for (int p = lane; p < nc; p += 64) {
                const unsigned long long pk = s_cand[p];
                if ((c == 0 || pk > prev) && pk < best) best = pk;
            }
            best = wave_min_u64(best);
            prev = best;
            csm[c] = __uint_as_float((unsigned)(best >> 32));
            if (lane == 0) {
                const unsigned lo = (unsigned)best;
                s_pos[c]  = (int)(lo >> 1);
                s_sign[c] = (int)(lo & 1u);
            }
        }
    } else {
        // exact fallback: wave0 rescans full row
#pragma unroll
        for (int c = 0; c < KK; c++) {
            unsigned long long best = ~0ull;
            for (int p = lane; p < LDIM; p += 64) {
                const float v    = row[p];
                const float cost = fabsf(v);
                const unsigned long long pk =
                    ((unsigned long long)__float_as_uint(cost) << 32)
                    | (unsigned)((p << 1) | (v > 0.f ? 1 : 0));
                if ((c == 0 || pk > prev) && pk < best) best = pk;
            }
            best = wave_min_u64(best);
            prev = best;
            csm[c] = __uint_as_float((unsigned)(best >> 32));
            if (lane == 0) {
                const unsigned lo = (unsigned)best;
                s_pos[c]  = (int)(lo >> 1);
                s_sign[c] = (int)(lo & 1u);
            }
        }
    }

    // stage 2: 1024 subset sums, m = (lane<<4)|i, ascending-j accumulation
    float sums[16];
#pragma unroll
    for (int i = 0; i < 16; i++) {
        const int m = (lane << 4) | i;
        float acc = 0.f;
#pragma unroll
        for (int j = 0; j < KK; j++) acc += (m & (1 << j)) ? csm[j] : 0.f;
        sums[i] = acc;
    }

    float zc[KK];
    unsigned long long prev2 = 0ull;
#pragma unroll
    for (int c = 0; c < KK; c++) {
        unsigned long long best = ~0ull;
#pragma unroll
        for (int i = 0; i < 16; i++) {
            const unsigned long long pk =
                ((unsigned long long)__float_as_uint(sums[i]) << 32)
                | (unsigned)((lane << 4) | i);
            if ((c == 0 || pk > prev2) && pk < best) best = pk;
        }
        best = wave_min_u64(best);
        prev2 = best;
        zc[c] = S0 - __uint_as_float((unsigned)(best >> 32));
        if (lane == 0) s_bestm[c] = (int)((unsigned)best & 1023u);
    }

    if (lane == 0) {
        float acc = 0.f; int ks = 0;
#pragma unroll
        for (int r = 1; r <= KK; r++) {
            acc += zc[r-1];
            if (1.f + (float)r * zc[r-1] > acc) ks++;
        }
        float acc2 = 0.f;
#pragma unroll
        for (int r = 0; r < KK; r++) if (r < ks) acc2 += zc[r];
        const float tau = (acc2 - 1.f) / (float)ks;
        float entl = 0.f;
        float* drow = distr + b * KK;
#pragma unroll
        for (int c = 0; c < KK; c++) {
            float p = zc[c] - tau;
            p = p > 0.f ? p : 0.f;
            drow[c] = p;
            if (p > 0.f) entl -= p * logf(p);
        }
        entp[b] = entl;

        unsigned* mrow = meta + b * KK;
#pragma unroll
        for (int s = 0; s < KK; s++) {
            unsigned fm = 0u;
#pragma unroll
            for (int c = 0; c < KK; c++)
                fm |= (((unsigned)s_bestm[c] >> s) & 1u) << c;
            mrow[s] = (unsigned)s_pos[s] | (fm << 12) | ((unsigned)s_sign[s] << 22);
        }
    }
}

// ============================================================================
// Kernel 2: fill-shaped writer. Block (c,b) writes the contiguous 16 KB plane
// bv[b][c][:]. No logits read — unpacks base bits, XORs flips in-register.
// ~16 VGPR, 552 B LDS, 4 linear 1KB/wave stores per wave. Grid (KK, NB).
// ============================================================================
__global__ __launch_bounds__(TPB) void bv_writer(
    const unsigned* __restrict__ basebits,
    const unsigned* __restrict__ meta,
    float* __restrict__ bv)
{
    __shared__ unsigned s_base[128];
    __shared__ unsigned s_m[KK];
    const int c = blockIdx.x;
    const int b = blockIdx.y;
    const int t = threadIdx.x;

    if (t < 128) s_base[t] = basebits[b * 128 + t];
    else if (t < 128 + KK) s_m[t - 128] = meta[b * KK + (t - 128)];
    __syncthreads();

    // my 16 cols: col = (u<<10) + 4t + e  <->  bit 4u+e of 'bits'
    unsigned bits = 0u;
#pragma unroll
    for (int u = 0; u < 4; u++)
        bits |= ((s_base[(u << 5) + (t >> 3)] >> (4 * (t & 7))) & 0xFu) << (4 * u);

    // flips: value at pos[s] on row c toggles iff fm_s bit c -> bit XOR
#pragma unroll
    for (int s = 0; s < KK; s++) {
        const unsigned m   = s_m[s];
        const int      pos = (int)(m & 0xFFFu);
        const unsigned flp = (m >> (12 + c)) & 1u;
        if (((pos & 1023) >> 2) == t)
            bits ^= flp << (4 * (pos >> 10) + (pos & 3));
    }

    float* out = bv + ((size_t)b * KK + c) * LDIM + (t << 2);
#pragma unroll
    for (int u = 0; u < 4; u++) {
        fx4 v;
        v.x = (bits >> (4*u + 0)) & 1u ? 1.f : 0.f;
        v.y = (bits >> (4*u + 1)) & 1u ? 1.f : 0.f;
        v.z = (bits >> (4*u + 2)) & 1u ? 1.f : 0.f;
        v.w = (bits >> (4*u + 3)) & 1u ? 1.f : 0.f;
        *(fx4*)(out + (u << 10)) = v;
    }
}

__global__ __launch_bounds__(256) void ent_reduce(
    const float* __restrict__ ws, float* __restrict__ ent)
{
    __shared__ float sw[4];
    const int t = threadIdx.x, lane = t & 63, wv = t >> 6;
    float s = 0.f;
    for (int i = t; i < NB; i += 256) s += ws[i];
#pragma unroll
    for (int off = 1; off < 64; off <<= 1) s += __shfl_xor(s, off, 64);
    if (lane == 0) sw[wv] = s;
    __syncthreads();
    if (t == 0) *ent = (sw[0] + sw[1] + sw[2] + sw[3]) * (1.0f / (float)NB);
}

// ============================================================================
// Fallback fused kernel (round-4, verified passing) for tiny/absent workspace.
// ============================================================================
__global__ __launch_bounds__(TPB) void topk_sparsemax_fused(
    const float* __restrict__ logits,
    float* __restrict__ bv,
    float* __restrict__ distr,
    float* __restrict__ ent)
{
    __shared__ float s_wsum[4];
    __shared__ int   s_pos[KK];
    __shared__ int   s_sign[KK];
    __shared__ int   s_bestm[KK];
    __shared__ int   s_cnt;
    __shared__ unsigned long long s_cand[CAP];

    const int b    = blockIdx.x;
    const int t    = threadIdx.x;
    const int lane = t & 63;
    const int wv   = t >> 6;
    const float* __restrict__ row = logits + (size_t)b * LDIM;

    float vals[16];
#pragma unroll
    for (int q = 0; q < 4; q++) {
        const float4 f = *(const float4*)(row + (q << 10) + (t << 2));
        vals[q*4+0] = f.x; vals[q*4+1] = f.y; vals[q*4+2] = f.z; vals[q*4+3] = f.w;
    }

    float s0 = 0.f;
#pragma unroll
    for (int i = 0; i < 16; i++) s0 += vals[i] > 0.f ? vals[i] : 0.f;
#pragma unroll
    for (int off = 1; off < 64; off <<= 1) s0 += __shfl_xor(s0, off, 64);
    if (lane == 0) s_wsum[wv] = s0;

    float T = 0.02f;
    int cnt = 0;
    for (int attempt = 0; attempt < 15; attempt++) {
        if (t == 0) s_cnt = 0;
        __syncthreads();
#pragma unroll
        for (int i = 0; i < 16; i++) {
            const float v    = vals[i];
            const float cost = fabsf(v);
            if (cost < T) {
                const int idx = ((i >> 2) << 10) + (t << 2) + (i & 3);
                const unsigned long long pk =
                    ((unsigned long long)__float_as_uint(cost) << 32)
                    | (unsigned)((idx << 1) | (v > 0.f ? 1 : 0));
                const int p = atomicAdd(&s_cnt, 1);
                if (p < CAP) s_cand[p] = pk;
            }
        }
        __syncthreads();
        cnt = s_cnt;
        if (cnt >= KK && cnt <= CAP) break;
        T = (cnt < KK) ? T * 4.0f : T * 0.25f;
        __syncthreads();
    }

    if (wv == 0) {
        const float S0 = (s_wsum[0] + s_wsum[1]) + (s_wsum[2] + s_wsum[3]);
        float csm[KK];
        unsigned long long prev = 0ull;
        if (cnt >= KK && cnt <= CAP) {
            const int nc = cnt;
#pragma unroll
            for (int c = 0; c < KK; c++) {
                unsigned long long best = ~0ull;
                for (int p = lane; p < nc; p += 64) {
                    const unsigned long long pk = s_cand[p];
                    if ((c == 0 || pk > prev) && pk < best) best = pk;
                }
                best = wave_min_u64(best);
                prev = best;
                csm[c] = __uint_as_float((unsigned)(best >> 32));
                if (lane == 0) {
                    const unsigned lo = (unsigned)best;
                    s_pos[c]  = (int)(lo >> 1);
                    s_sign[c] = (int)(lo & 1u);
                }
            }
        } else {
#pragma unroll
            for (int c = 0; c < KK; c++) {
                unsigned long long best = ~0ull;
                for (int p = lane; p < LDIM; p += 64) {
                    const float v    = row[p];
                    const float cost = fabsf(v);
                    const unsigned long long pk =
                        ((unsigned long long)__float_as_uint(cost) << 32)
                        | (unsigned)((p << 1) | (v > 0.f ? 1 : 0));
                    if ((c == 0 || pk > prev) && pk < best) best = pk;
                }
                best = wave_min_u64(best);
                prev = best;
                csm[c] = __uint_as_float((unsigned)(best >> 32));
                if (lane == 0) {
                    const unsigned lo = (unsigned)best;
                    s_pos[c]  = (int)(lo >> 1);
                    s_sign[c] = (int)(lo & 1u);
                }
            }
        }
        float sums[16];
#pragma unroll
        for (int i = 0; i < 16; i++) {
            const int m = (lane << 4) | i;
            float acc = 0.f;
#pragma unroll
            for (int j = 0; j < KK; j++) acc += (m & (1 << j)) ? csm[j] : 0.f;
            sums[i] = acc;
        }
        float zc[KK];
        unsigned long long prev2 = 0ull;
#pragma unroll
        for (int c = 0; c < KK; c++) {
            unsigned long long best = ~0ull;
#pragma unroll
            for (int i = 0; i < 16; i++) {
                const unsigned long long pk =
                    ((unsigned long long)__float_as_uint(sums[i]) << 32)
                    | (unsigned)((lane << 4) | i);
                if ((c == 0 || pk > prev2) && pk < best) best = pk;
            }
            best = wave_min_u64(best);
            prev2 = best;
            zc[c] = S0 - __uint_as_float((unsigned)(best >> 32));
            if (lane == 0) s_bestm[c] = (int)((unsigned)best & 1023u);
        }
        if (lane == 0) {
            float acc = 0.f; int ks = 0;
#pragma unroll
            for (int r = 1; r <= KK; r++) {
                acc += zc[r-1];
                if (1.f + (float)r * zc[r-1] > acc) ks++;
            }
            float acc2 = 0.f;
#pragma unroll
            for (int r = 0; r < KK; r++) if (r < ks) acc2 += zc[r];
            const float tau = (acc2 - 1.f) / (float)ks;
            float entl = 0.f;
            float* drow = distr + b * KK;
#pragma unroll
            for (int c = 0; c < KK; c++) {
                float p = zc[c] - tau;
                p = p > 0.f ? p : 0.f;
                drow[c] = p;
                if (p > 0.f) entl -= p * logf(p);
            }
            atomicAdd(ent, entl * (1.0f / (float)NB));
        }
    }

    __syncthreads();

    unsigned fm[KK];
#pragma unroll
    for (int j = 0; j < KK; j++) {
        unsigned m = 0u;
#pragma unroll
        for (int c = 0; c < KK; c++)
            m |= (((unsigned)s_bestm[c] >> j) & 1u) << c;
        fm[j] = m;
    }
    int posr[KK], sgnr[KK];
#pragma unroll
    for (int j = 0; j < KK; j++) { posr[j] = s_pos[j]; sgnr[j] = s_sign[j]; }

    unsigned rowflip[16]; float flipval[16]; float basef[16];
#pragma unroll
    for (int i = 0; i < 16; i++) {
        const int col = ((i >> 2) << 10) + (t << 2) + (i & 3);
        unsigned rfm = 0u; float fvv = 0.f;
#pragma unroll
        for (int j = 0; j < KK; j++) {
            if (posr[j] == col) { rfm = fm[j]; fvv = sgnr[j] ? 0.f : 1.f; }
        }
        rowflip[i] = rfm; flipval[i] = fvv;
        basef[i]   = vals[i] > 0.f ? 1.f : 0.f;
    }

    float* out0 = bv + (size_t)b * (KK * LDIM);
#pragma unroll
    for (int c = 0; c < KK; c++) {
        float* orow = out0 + c * LDIM + (t << 2);
#pragma unroll
        for (int q = 0; q < 4; q++) {
            fx4 v;
            v.x = ((rowflip[q*4+0] >> c) & 1u) ? flipval[q*4+0] : basef[q*4+0];
            v.y = ((rowflip[q*4+1] >> c) & 1u) ? flipval[q*4+1] : basef[q*4+1];
            v.z = ((rowflip[q*4+2] >> c) & 1u) ? flipval[q*4+2] : basef[q*4+2];
            v.w = ((rowflip[q*4+3] >> c) & 1u) ? flipval[q*4+3] : basef[q*4+3];
            __builtin_nontemporal_store(v, (fx4*)(orow + (q << 10)));
        }
    }
}

extern "C" void kernel_launch(void* const* d_in, const int* in_sizes, int n_in,
                              void* d_out, int out_size, void* d_ws, size_t ws_size,
                              hipStream_t stream)
{
    const float* logits = (const float*)d_in[0];
    float* out   = (float*)d_out;
    float* bv    = out;
    float* distr = out + (size_t)NB * KK * LDIM;
    float* ent   = distr + (size_t)NB * KK;

    const size_t need = (size_t)NB * sizeof(float)              // entropy partials
                      + (size_t)NB * KK * sizeof(unsigned)      // packed meta
                      + (size_t)NB * 128 * sizeof(unsigned);    // base bitmasks
    if (ws_size >= need) {
        float*    entp = (float*)d_ws;
        unsigned* meta = (unsigned*)((float*)d_ws + NB);
        unsigned* bbit = meta + (size_t)NB * KK;
        select_rows<<<dim3(NB), dim3(TPB), 0, stream>>>(logits, distr, entp, meta, bbit);
        bv_writer <<<dim3(KK, NB), dim3(TPB), 0, stream>>>(bbit, meta, bv);
        ent_reduce<<<dim3(1), dim3(256), 0, stream>>>(entp, ent);
    } else {
        (void)hipMemsetAsync(ent, 0, sizeof(float), stream);
        topk_sparsemax_fused<<<dim3(NB), dim3(TPB), 0, stream>>>(logits, bv, distr, ent);
    }
}

// Round 7
// 716.095 us; speedup vs baseline: 1.0007x; 1.0007x over previous
//
#include <hip/hip_runtime.h>
#include <stdint.h>

#define NB   4096   // batch rows
#define LDIM 4096   // latent dim
#define KK   10     // k
#define TPB  256
#define CAP  1024   // survivor buffer entries (u64) -> 8 KB LDS

#define WPR  (KK * 128)                    // corrected-bitplane words per row (1280)
#define TOT4 ((size_t)NB * KK * LDIM / 4)  // total float4 elements of bv

typedef float fx4 __attribute__((ext_vector_type(4)));

__device__ __forceinline__ unsigned long long wave_min_u64(unsigned long long v) {
#pragma unroll
    for (int off = 1; off < 64; off <<= 1) {
        const unsigned long long o = __shfl_xor(v, off, 64);
        if (o < v) v = o;
    }
    return v;
}

// ============================================================================
// Kernel 1: selection + corrected bitplane. One block per row. Emits:
//   fullbits[b][c][w] : bit j of word w == bv[b][c][32w+j]  (flips applied)
//   distr row + entropy partial
// ============================================================================
__global__ __launch_bounds__(TPB) void select_rows(
    const float* __restrict__ logits,
    float* __restrict__ distr,      // [NB, KK]
    float* __restrict__ entp,       // [NB]
    unsigned* __restrict__ fullbits)// [NB, KK, 128]
{
    __shared__ float s_wsum[4];
    __shared__ int   s_pos[KK];
    __shared__ int   s_sign[KK];
    __shared__ int   s_bestm[KK];
    __shared__ int   s_cnt;
    __shared__ unsigned s_base[128];
    __shared__ unsigned long long s_cand[CAP];

    const int b    = blockIdx.x;
    const int t    = threadIdx.x;
    const int lane = t & 63;
    const int wv   = t >> 6;
    const float* __restrict__ row = logits + (size_t)b * LDIM;

    // coalesced row load: element i=4q+e -> col (q<<10) + 4t + e
    float vals[16];
#pragma unroll
    for (int q = 0; q < 4; q++) {
        const float4 f = *(const float4*)(row + (q << 10) + (t << 2));
        vals[q*4+0] = f.x; vals[q*4+1] = f.y; vals[q*4+2] = f.z; vals[q*4+3] = f.w;
    }

    // S0 = sum of positive logits (identical reduction order to passing kernel)
    float s0 = 0.f;
#pragma unroll
    for (int i = 0; i < 16; i++) s0 += vals[i] > 0.f ? vals[i] : 0.f;
#pragma unroll
    for (int off = 1; off < 64; off <<= 1) s0 += __shfl_xor(s0, off, 64);
    if (lane == 0) s_wsum[wv] = s0;

    if (t < 128) s_base[t] = 0u;
    __syncthreads();
    // base-sign bitmask: col -> word col>>5, bit col&31
#pragma unroll
    for (int q = 0; q < 4; q++) {
        unsigned nib = 0u;
#pragma unroll
        for (int e = 0; e < 4; e++)
            nib |= (vals[q*4+e] > 0.f ? 1u : 0u) << e;
        atomicOr(&s_base[(q << 5) + (t >> 3)], nib << (4 * (t & 7)));
    }

    // threshold compaction (exact; retry + full-rescan fallback)
    float T = 0.02f;
    int cnt = 0;
    for (int attempt = 0; attempt < 15; attempt++) {
        if (t == 0) s_cnt = 0;
        __syncthreads();
#pragma unroll
        for (int i = 0; i < 16; i++) {
            const float v    = vals[i];
            const float cost = fabsf(v);
            if (cost < T) {
                const int idx = ((i >> 2) << 10) + (t << 2) + (i & 3);
                const unsigned long long pk =
                    ((unsigned long long)__float_as_uint(cost) << 32)
                    | (unsigned)((idx << 1) | (v > 0.f ? 1 : 0));
                const int p = atomicAdd(&s_cnt, 1);
                if (p < CAP) s_cand[p] = pk;
            }
        }
        __syncthreads();
        cnt = s_cnt;
        if (cnt >= KK && cnt <= CAP) break;
        T = (cnt < KK) ? T * 4.0f : T * 0.25f;
        __syncthreads();
    }

    if (wv == 0) {
        const float S0 = (s_wsum[0] + s_wsum[1]) + (s_wsum[2] + s_wsum[3]);
        float csm[KK];
        unsigned long long prev = 0ull;

        if (cnt >= KK && cnt <= CAP) {
            const int nc = cnt;
#pragma unroll
            for (int c = 0; c < KK; c++) {
                unsigned long long best = ~0ull;
                for (int p = lane; p < nc; p += 64) {
                    const unsigned long long pk = s_cand[p];
                    if ((c == 0 || pk > prev) && pk < best) best = pk;
                }
                best = wave_min_u64(best);
                prev = best;
                csm[c] = __uint_as_float((unsigned)(best >> 32));
                if (lane == 0) {
                    const unsigned lo = (unsigned)best;
                    s_pos[c]  = (int)(lo >> 1);
                    s_sign[c] = (int)(lo & 1u);
                }
            }
        } else {
            // exact fallback: wave0 rescans full row
#pragma unroll
            for (int c = 0; c < KK; c++) {
                unsigned long long best = ~0ull;
                for (int p = lane; p < LDIM; p += 64) {
                    const float v    = row[p];
                    const float cost = fabsf(v);
                    const unsigned long long pk =
                        ((unsigned long long)__float_as_uint(cost) << 32)
                        | (unsigned)((p << 1) | (v > 0.f ? 1 : 0));
                    if ((c == 0 || pk > prev) && pk < best) best = pk;
                }
                best = wave_min_u64(best);
                prev = best;
                csm[c] = __uint_as_float((unsigned)(best >> 32));
                if (lane == 0) {
                    const unsigned lo = (unsigned)best;
                    s_pos[c]  = (int)(lo >> 1);
                    s_sign[c] = (int)(lo & 1u);
                }
            }
        }

        // stage 2: 1024 subset sums, m = (lane<<4)|i, ascending-j accumulation
        float sums[16];
#pragma unroll
        for (int i = 0; i < 16; i++) {
            const int m = (lane << 4) | i;
            float acc = 0.f;
#pragma unroll
            for (int j = 0; j < KK; j++) acc += (m & (1 << j)) ? csm[j] : 0.f;
            sums[i] = acc;
        }

        float zc[KK];
        unsigned long long prev2 = 0ull;
#pragma unroll
        for (int c = 0; c < KK; c++) {
            unsigned long long best = ~0ull;
#pragma unroll
            for (int i = 0; i < 16; i++) {
                const unsigned long long pk =
                    ((unsigned long long)__float_as_uint(sums[i]) << 32)
                    | (unsigned)((lane << 4) | i);
                if ((c == 0 || pk > prev2) && pk < best) best = pk;
            }
            best = wave_min_u64(best);
            prev2 = best;
            zc[c] = S0 - __uint_as_float((unsigned)(best >> 32));
            if (lane == 0) s_bestm[c] = (int)((unsigned)best & 1023u);
        }

        if (lane == 0) {
            float acc = 0.f; int ks = 0;
#pragma unroll
            for (int r = 1; r <= KK; r++) {
                acc += zc[r-1];
                if (1.f + (float)r * zc[r-1] > acc) ks++;
            }
            float acc2 = 0.f;
#pragma unroll
            for (int r = 0; r < KK; r++) if (r < ks) acc2 += zc[r];
            const float tau = (acc2 - 1.f) / (float)ks;
            float entl = 0.f;
            float* drow = distr + b * KK;
#pragma unroll
            for (int c = 0; c < KK; c++) {
                float p = zc[c] - tau;
                p = p > 0.f ? p : 0.f;
                drow[c] = p;
                if (p > 0.f) entl -= p * logf(p);
            }
            entp[b] = entl;
        }
    }

    // publish selection to all waves, then emit corrected bitplane (1280 words)
    __syncthreads();
    unsigned* frow = fullbits + (size_t)b * WPR;
#pragma unroll
    for (int r = 0; r < WPR / TPB; r++) {
        const int i = t + r * TPB;      // i = c*128 + w ; consecutive t -> coalesced
        const int c = i >> 7;
        const int w = i & 127;
        unsigned word = s_base[w];
#pragma unroll
        for (int s = 0; s < KK; s++) {
            const int ps = s_pos[s];
            // toggle bit (ps&31) iff ps lies in word w AND subset of row c flips slot s
            const unsigned hit = (unsigned)((ps >> 5) == w) & ((unsigned)(s_bestm[c] >> s) & 1u);
            word ^= hit << (ps & 31);
        }
        frow[i] = word;
    }
}

// ============================================================================
// Kernel 2: fill-clone expander. Flat grid-stride over float4 elements of bv.
// word = fullbits[f>>3] (L1-broadcast), nibble -> 4 floats, NT 16 B store.
// No div/mod, no LDS, no barrier, ~12 VGPR.
// ============================================================================
#define EXP_BLOCKS 2048
__global__ __launch_bounds__(TPB) void bv_expand(
    const unsigned* __restrict__ fullbits,
    float* __restrict__ bv)
{
    const size_t stride = (size_t)EXP_BLOCKS * TPB;
    for (size_t f = (size_t)blockIdx.x * TPB + threadIdx.x; f < TOT4; f += stride) {
        const unsigned word = fullbits[f >> 3];
        const unsigned nib  = (word >> ((f & 7) << 2)) & 0xFu;
        fx4 v;
        v.x = (nib & 1u) ? 1.f : 0.f;
        v.y = (nib & 2u) ? 1.f : 0.f;
        v.z = (nib & 4u) ? 1.f : 0.f;
        v.w = (nib & 8u) ? 1.f : 0.f;
        __builtin_nontemporal_store(v, (fx4*)(bv + (f << 2)));
    }
}

__global__ __launch_bounds__(256) void ent_reduce(
    const float* __restrict__ ws, float* __restrict__ ent)
{
    __shared__ float sw[4];
    const int t = threadIdx.x, lane = t & 63, wv = t >> 6;
    float s = 0.f;
    for (int i = t; i < NB; i += 256) s += ws[i];
#pragma unroll
    for (int off = 1; off < 64; off <<= 1) s += __shfl_xor(s, off, 64);
    if (lane == 0) sw[wv] = s;
    __syncthreads();
    if (t == 0) *ent = (sw[0] + sw[1] + sw[2] + sw[3]) * (1.0f / (float)NB);
}

// ============================================================================
// Fallback fused kernel (round-4, verified passing) for tiny/absent workspace.
// ============================================================================
__global__ __launch_bounds__(TPB) void topk_sparsemax_fused(
    const float* __restrict__ logits,
    float* __restrict__ bv,
    float* __restrict__ distr,
    float* __restrict__ ent)
{
    __shared__ float s_wsum[4];
    __shared__ int   s_pos[KK];
    __shared__ int   s_sign[KK];
    __shared__ int   s_bestm[KK];
    __shared__ int   s_cnt;
    __shared__ unsigned long long s_cand[CAP];

    const int b    = blockIdx.x;
    const int t    = threadIdx.x;
    const int lane = t & 63;
    const int wv   = t >> 6;
    const float* __restrict__ row = logits + (size_t)b * LDIM;

    float vals[16];
#pragma unroll
    for (int q = 0; q < 4; q++) {
        const float4 f = *(const float4*)(row + (q << 10) + (t << 2));
        vals[q*4+0] = f.x; vals[q*4+1] = f.y; vals[q*4+2] = f.z; vals[q*4+3] = f.w;
    }

    float s0 = 0.f;
#pragma unroll
    for (int i = 0; i < 16; i++) s0 += vals[i] > 0.f ? vals[i] : 0.f;
#pragma unroll
    for (int off = 1; off < 64; off <<= 1) s0 += __shfl_xor(s0, off, 64);
    if (lane == 0) s_wsum[wv] = s0;

    float T = 0.02f;
    int cnt = 0;
    for (int attempt = 0; attempt < 15; attempt++) {
        if (t == 0) s_cnt = 0;
        __syncthreads();
#pragma unroll
        for (int i = 0; i < 16; i++) {
            const float v    = vals[i];
            const float cost = fabsf(v);
            if (cost < T) {
                const int idx = ((i >> 2) << 10) + (t << 2) + (i & 3);
                const unsigned long long pk =
                    ((unsigned long long)__float_as_uint(cost) << 32)
                    | (unsigned)((idx << 1) | (v > 0.f ? 1 : 0));
                const int p = atomicAdd(&s_cnt, 1);
                if (p < CAP) s_cand[p] = pk;
            }
        }
        __syncthreads();
        cnt = s_cnt;
        if (cnt >= KK && cnt <= CAP) break;
        T = (cnt < KK) ? T * 4.0f : T * 0.25f;
        __syncthreads();
    }

    if (wv == 0) {
        const float S0 = (s_wsum[0] + s_wsum[1]) + (s_wsum[2] + s_wsum[3]);
        float csm[KK];
        unsigned long long prev = 0ull;
        if (cnt >= KK && cnt <= CAP) {
            const int nc = cnt;
#pragma unroll
            for (int c = 0; c < KK; c++) {
                unsigned long long best = ~0ull;
                for (int p = lane; p < nc; p += 64) {
                    const unsigned long long pk = s_cand[p];
                    if ((c == 0 || pk > prev) && pk < best) best = pk;
                }
                best = wave_min_u64(best);
                prev = best;
                csm[c] = __uint_as_float((unsigned)(best >> 32));
                if (lane == 0) {
                    const unsigned lo = (unsigned)best;
                    s_pos[c]  = (int)(lo >> 1);
                    s_sign[c] = (int)(lo & 1u);
                }
            }
        } else {
#pragma unroll
            for (int c = 0; c < KK; c++) {
                unsigned long long best = ~0ull;
                for (int p = lane; p < LDIM; p += 64) {
                    const float v    = row[p];
                    const float cost = fabsf(v);
                    const unsigned long long pk =
                        ((unsigned long long)__float_as_uint(cost) << 32)
                        | (unsigned)((p << 1) | (v > 0.f ? 1 : 0));
                    if ((c == 0 || pk > prev) && pk < best) best = pk;
                }
                best = wave_min_u64(best);
                prev = best;
                csm[c] = __uint_as_float((unsigned)(best >> 32));
                if (lane == 0) {
                    const unsigned lo = (unsigned)best;
                    s_pos[c]  = (int)(lo >> 1);
                    s_sign[c] = (int)(lo & 1u);
                }
            }
        }
        float sums[16];
#pragma unroll
        for (int i = 0; i < 16; i++) {
            const int m = (lane << 4) | i;
            float acc = 0.f;
#pragma unroll
            for (int j = 0; j < KK; j++) acc += (m & (1 << j)) ? csm[j] : 0.f;
            sums[i] = acc;
        }
        float zc[KK];
        unsigned long long prev2 = 0ull;
#pragma unroll
        for (int c = 0; c < KK; c++) {
            unsigned long long best = ~0ull;
#pragma unroll
            for (int i = 0; i < 16; i++) {
                const unsigned long long pk =
                    ((unsigned long long)__float_as_uint(sums[i]) << 32)
                    | (unsigned)((lane << 4) | i);
                if ((c == 0 || pk > prev2) && pk < best) best = pk;
            }
            best = wave_min_u64(best);
            prev2 = best;
            zc[c] = S0 - __uint_as_float((unsigned)(best >> 32));
            if (lane == 0) s_bestm[c] = (int)((unsigned)best & 1023u);
        }
        if (lane == 0) {
            float acc = 0.f; int ks = 0;
#pragma unroll
            for (int r = 1; r <= KK; r++) {
                acc += zc[r-1];
                if (1.f + (float)r * zc[r-1] > acc) ks++;
            }
            float acc2 = 0.f;
#pragma unroll
            for (int r = 0; r < KK; r++) if (r < ks) acc2 += zc[r];
            const float tau = (acc2 - 1.f) / (float)ks;
            float entl = 0.f;
            float* drow = distr + b * KK;
#pragma unroll
            for (int c = 0; c < KK; c++) {
                float p = zc[c] - tau;
                p = p > 0.f ? p : 0.f;
                drow[c] = p;
                if (p > 0.f) entl -= p * logf(p);
            }
            atomicAdd(ent, entl * (1.0f / (float)NB));
        }
    }

    __syncthreads();

    unsigned fm[KK];
#pragma unroll
    for (int j = 0; j < KK; j++) {
        unsigned m = 0u;
#pragma unroll
        for (int c = 0; c < KK; c++)
            m |= (((unsigned)s_bestm[c] >> j) & 1u) << c;
        fm[j] = m;
    }
    int posr[KK], sgnr[KK];
#pragma unroll
    for (int j = 0; j < KK; j++) { posr[j] = s_pos[j]; sgnr[j] = s_sign[j]; }

    unsigned rowflip[16]; float flipval[16]; float basef[16];
#pragma unroll
    for (int i = 0; i < 16; i++) {
        const int col = ((i >> 2) << 10) + (t << 2) + (i & 3);
        unsigned rfm = 0u; float fvv = 0.f;
#pragma unroll
        for (int j = 0; j < KK; j++) {
            if (posr[j] == col) { rfm = fm[j]; fvv = sgnr[j] ? 0.f : 1.f; }
        }
        rowflip[i] = rfm; flipval[i] = fvv;
        basef[i]   = vals[i] > 0.f ? 1.f : 0.f;
    }

    float* out0 = bv + (size_t)b * (KK * LDIM);
#pragma unroll
    for (int c = 0; c < KK; c++) {
        float* orow = out0 + c * LDIM + (t << 2);
#pragma unroll
        for (int q = 0; q < 4; q++) {
            fx4 v;
            v.x = ((rowflip[q*4+0] >> c) & 1u) ? flipval[q*4+0] : basef[q*4+0];
            v.y = ((rowflip[q*4+1] >> c) & 1u) ? flipval[q*4+1] : basef[q*4+1];
            v.z = ((rowflip[q*4+2] >> c) & 1u) ? flipval[q*4+2] : basef[q*4+2];
            v.w = ((rowflip[q*4+3] >> c) & 1u) ? flipval[q*4+3] : basef[q*4+3];
            __builtin_nontemporal_store(v, (fx4*)(orow + (q << 10)));
        }
    }
}

extern "C" void kernel_launch(void* const* d_in, const int* in_sizes, int n_in,
                              void* d_out, int out_size, void* d_ws, size_t ws_size,
                              hipStream_t stream)
{
    const float* logits = (const float*)d_in[0];
    float* out   = (float*)d_out;
    float* bv    = out;
    float* distr = out + (size_t)NB * KK * LDIM;
    float* ent   = distr + (size_t)NB * KK;

    const size_t need = (size_t)NB * sizeof(float)              // entropy partials
                      + (size_t)NB * WPR * sizeof(unsigned);    // corrected bitplanes
    if (ws_size >= need) {
        float*    entp = (float*)d_ws;
        unsigned* bits = (unsigned*)((float*)d_ws + NB);
        select_rows<<<dim3(NB), dim3(TPB), 0, stream>>>(logits, distr, entp, bits);
        bv_expand <<<dim3(EXP_BLOCKS), dim3(TPB), 0, stream>>>(bits, bv);
        ent_reduce<<<dim3(1), dim3(256), 0, stream>>>(entp, ent);
    } else {
        (void)hipMemsetAsync(ent, 0, sizeof(float), stream);
        topk_sparsemax_fused<<<dim3(NB), dim3(TPB), 0, stream>>>(logits, bv, distr, ent);
    }
}